// Round 11
// baseline (286.430 us; speedup 1.0000x reference)
//
#include <hip/hip_runtime.h>
#include <math.h>

#define N_PTS 2048
#define K_NN  20
#define K_D   10              // per-slice kept depth
#define WTOT  819200          // total weight elements across the 5 tensors

typedef unsigned short u16;
typedef unsigned int   u32;
typedef _Float16 f16;
using half8   = __attribute__((ext_vector_type(8))) _Float16;
using floatx4 = __attribute__((ext_vector_type(4))) float;

// Weights: split fp16.  w ~= hi + lo/1024, |err| ~ 2^-24 |w|.
__device__ __forceinline__ void split2h(float v, f16& h, f16& l) {
    h = (f16)v;
    l = (f16)((v - (float)h) * 1024.0f);
}

// nd must be bit-identical in phase 1 and phase 2b.
__device__ __forceinline__ float neg_dist(float4 q2, float4 c) {
    return fmaf(q2.x, c.x, fmaf(q2.y, c.y, fmaf(q2.z, c.z, -q2.w))) - c.w;
}

// ---------------------------------------------------------------------------
// prep_kernel = KNN (blocks 0..1023) + weight convert/swizzle (blocks 1024+).
// Also zeroes nm_acc and the head sync counter every launch (replay-safe).
// ---------------------------------------------------------------------------
__global__ __launch_bounds__(256) void prep_kernel(
    const float* __restrict__ pts, float* __restrict__ m_out,
    const float* __restrict__ bd0, const float* __restrict__ bW0,
    const float* __restrict__ bd1, const float* __restrict__ bW1,
    const float* __restrict__ bWs, u16* __restrict__ Wswz,
    float* __restrict__ nm_acc, int* __restrict__ sync_cnt)
{
    __shared__ float4 sp[N_PTS];                      // 32 KB (knn branch only)
    if (blockIdx.x >= 1024) {
        int i = (blockIdx.x - 1024) * 256 + threadIdx.x;
        if (i >= WTOT) return;
        if (i < 7680) nm_acc[i] = 0.f;
        if (i == 0) sync_cnt[0] = 0;
        float v; int base, K, local;
        if (i < 327680)      { int rel = i;          base = (rel/65536)*65536;            local = rel%65536; K = 256; v = bd0[rel]; }
        else if (i < 491520) { int rel = i - 327680; base = 327680 + (rel/32768)*32768;   local = rel%32768; K = 256; v = bW0[rel]; }
        else if (i < 573440) { int rel = i - 491520; base = 491520 + (rel/16384)*16384;   local = rel%16384; K = 128; v = bd1[rel]; }
        else if (i < 655360) { int rel = i - 573440; base = 573440 + (rel/16384)*16384;   local = rel%16384; K = 128; v = bW1[rel]; }
        else                 { int rel = i - 655360; base = 655360 + (rel/32768)*32768;   local = rel%32768; K = 256; v = bWs[rel]; }
        int m = local / K, k = local % K;
        int NKF = K >> 5;
        int mf = m >> 4, r = m & 15;
        int kf = k >> 5, q = (k >> 3) & 3, ii = k & 7;
        int lane = q*16 + r;
        int dst = base + ((mf*NKF + kf)*64 + lane)*8 + ii;
        f16 h, l; split2h(v, h, l);
        f16* W = (f16*)Wswz;
        W[dst] = h; W[WTOT + dst] = l;
        return;
    }

    // ---- KNN ----
    const int b     = blockIdx.x >> 8;
    const int qbase = (blockIdx.x & 255) << 3;
    const int ql    = threadIdx.x >> 5;
    const int sl    = threadIdx.x & 31;
    const float* pb = pts + (size_t)b * N_PTS * 3;
    for (int i = threadIdx.x; i < N_PTS; i += 256) {
        float x = pb[i*3+0], y = pb[i*3+1], z = pb[i*3+2];
        sp[i] = make_float4(x, y, z, x*x + y*y + z*z);
    }
    __syncthreads();

    const int n = qbase + ql;
    const float4 q = sp[n];
    const float4 q2 = make_float4(2.f*q.x, 2.f*q.y, 2.f*q.z, q.w);

    float t[K_D];
#pragma unroll
    for (int s = 0; s < K_D; ++s) t[s] = -INFINITY;

    for (int j = 0; j < N_PTS/32; ++j) {
        float4 c = sp[j*32 + sl];
        float v = neg_dist(q2, c);
#pragma unroll
        for (int s = 0; s < K_D; ++s) {
            float nx = (s < K_D-1) ? t[s+1] : INFINITY;
            t[s] = fminf(fmaxf(t[s], v), nx);
        }
    }

    float head = t[K_D-1];
    float T = -INFINITY;
#pragma unroll 1
    for (int e = 0; e < K_NN; ++e) {
        float v = head; int w = sl;
#pragma unroll
        for (int off = 1; off < 32; off <<= 1) {
            float vo = __shfl_xor(v, off);
            int   wo = __shfl_xor(w, off);
            bool take = (vo > v) || (vo == v && wo < w);
            v = take ? vo : v;
            w = take ? wo : w;
        }
        T = v;
        if (w == sl) {
#pragma unroll
            for (int s = K_D-1; s > 0; --s) t[s] = t[s-1];
            t[0] = -INFINITY;
            head = t[K_D-1];
        }
    }

    float sx = 0.f, sy = 0.f, sz = 0.f;
    for (int j = 0; j < N_PTS/32; ++j) {
        float4 c = sp[j*32 + sl];
        float v = neg_dist(q2, c);
        if (v >= T) { sx += c.x; sy += c.y; sz += c.z; }
    }
#pragma unroll
    for (int off = 1; off < 32; off <<= 1) {
        sx += __shfl_xor(sx, off);
        sy += __shfl_xor(sy, off);
        sz += __shfl_xor(sz, off);
    }
    if (sl == 0) {
        const float inv = 1.0f / (float)K_NN;
        const int pt = b * N_PTS + n;
        m_out[pt*3+0] = sx * inv;
        m_out[pt*3+1] = sy * inv;
        m_out[pt*3+2] = sz * inv;
    }
}

// ---------------------------------------------------------------------------
// MFMA GEMM cores, compile-time NK, depth-2 prefetch (3 rotating buffers).
// A-frags from L2 (swizzled), B from LDS.
// ---------------------------------------------------------------------------
template<int MF, int JF, int NK>
__device__ __forceinline__ void run_gemm_hi(
    const f16* __restrict__ Whi, size_t aoff,
    const f16* Blds, int bstride, int lane,
    floatx4 (&acc)[MF][JF])
{
    const int l15 = lane & 15;
    const int lq8 = (lane >> 4) * 8;
    half8 buf[3][MF];

    auto loada = [&](half8 (&dst)[MF], int kf) {
#pragma unroll
        for (int fm = 0; fm < MF; ++fm)
            dst[fm] = *(const half8*)(Whi + aoff + (size_t)(fm*NK + kf)*512 + (size_t)lane*8);
    };
    auto step = [&](half8 (&af)[MF], int kf) {
        half8 bq[JF];
#pragma unroll
        for (int fj = 0; fj < JF; ++fj)
            bq[fj] = *(const half8*)&Blds[(fj*16 + l15)*bstride + kf*32 + lq8];
#pragma unroll
        for (int fm = 0; fm < MF; ++fm)
#pragma unroll
            for (int fj = 0; fj < JF; ++fj)
                acc[fm][fj] = __builtin_amdgcn_mfma_f32_16x16x32_f16(af[fm], bq[fj], acc[fm][fj], 0, 0, 0);
    };

    loada(buf[0], 0);
    if (NK > 1) loada(buf[1], 1);
#pragma unroll
    for (int kf = 0; kf < NK; ++kf) {
        if (kf + 2 < NK) loada(buf[(kf+2)%3], kf+2);
        step(buf[kf%3], kf);
    }
}

template<int MF, int JF, int NK>
__device__ __forceinline__ void run_gemm_split(
    const f16* __restrict__ Whi, const f16* __restrict__ Wlo, size_t aoff,
    const f16* Blds, int bstride, int lane,
    floatx4 (&acc)[MF][JF], floatx4 (&accL)[MF][JF])
{
    const int l15 = lane & 15;
    const int lq8 = (lane >> 4) * 8;
    half8 buf[3][2*MF];

    auto loada = [&](half8 (&dst)[2*MF], int kf) {
#pragma unroll
        for (int fm = 0; fm < MF; ++fm) {
            size_t fo = aoff + (size_t)(fm*NK + kf)*512 + (size_t)lane*8;
            dst[fm*2+0] = *(const half8*)(Whi + fo);
            dst[fm*2+1] = *(const half8*)(Wlo + fo);
        }
    };
    auto step = [&](half8 (&af)[2*MF], int kf) {
        half8 bq[JF];
#pragma unroll
        for (int fj = 0; fj < JF; ++fj)
            bq[fj] = *(const half8*)&Blds[(fj*16 + l15)*bstride + kf*32 + lq8];
#pragma unroll
        for (int fm = 0; fm < MF; ++fm)
#pragma unroll
            for (int fj = 0; fj < JF; ++fj) {
                acc[fm][fj]  = __builtin_amdgcn_mfma_f32_16x16x32_f16(af[fm*2+0], bq[fj], acc[fm][fj], 0, 0, 0);
                accL[fm][fj] = __builtin_amdgcn_mfma_f32_16x16x32_f16(af[fm*2+1], bq[fj], accL[fm][fj], 0, 0, 0);
            }
    };

    loada(buf[0], 0);
    if (NK > 1) loada(buf[1], 1);
#pragma unroll
    for (int kf = 0; kf < NK; ++kf) {
        if (kf + 2 < NK) loada(buf[(kf+2)%3], kf+2);
        step(buf[kf%3], kf);
    }
}

__device__ __forceinline__ uint2 pack_res(floatx4 a, floatx4 aL) {
    u16 hh[4];
#pragma unroll
    for (int r = 0; r < 4; ++r) {
        f16 hv = (f16)(a[r] + aL[r] * (1.0f/1024.0f));
        hh[r] = *(u16*)&hv;
    }
    uint2 pv;
    pv.x = (u32)hh[0] | ((u32)hh[1] << 16);
    pv.y = (u32)hh[2] | ((u32)hh[3] << 16);
    return pv;
}

__device__ __forceinline__ uint2 pack_hi(floatx4 a) {
    u16 hh[4];
#pragma unroll
    for (int r = 0; r < 4; ++r) {
        f16 hv = (f16)a[r];
        hh[r] = *(u16*)&hv;
    }
    uint2 pv;
    pv.x = (u32)hh[0] | ((u32)hh[1] << 16);
    pv.y = (u32)hh[2] | ((u32)hh[3] << 16);
    return pv;
}

// ---------------------------------------------------------------------------
// Fused resnet block (round-9 structure, verified) + depth-2 A prefetch.
// do_head: last-arriving block (atomic counter) runs the final head; pool
// sums are read back with atomic loads (device-coherent, no stale-L2 risk).
// Last block also skips netOut stores (its net feeds only the pool).
// ---------------------------------------------------------------------------
__global__ __launch_bounds__(256, 2) void resblk_kernel(
    const u16* __restrict__ Wswz,
    int offD0, int offW0, int offD1, int offW1, int offWs,
    const f16* __restrict__ netIn, const float* __restrict__ nm_prev,
    const float* __restrict__ pts, const float* __restrict__ m_buf,
    const float* __restrict__ fcW,
    f16* __restrict__ netOut, float* __restrict__ nm_out, int blk0,
    int do_head, int* __restrict__ sync_cnt,
    const float* __restrict__ act_d, const float* __restrict__ fc_c,
    float* __restrict__ out)
{
    __shared__ struct {
        f16 X[48*264];                              // x (width 256), 25344 B
        union { f16 d[48*264]; float C[48*132]; } Y;
        f16 H[48*136];                              // h / y2 (width 128)
    } s;
    __shared__ int lastFlag;

    const int tid  = threadIdx.x;
    const int jb   = blockIdx.x * 48;
    const int bB   = blockIdx.x >> 7;               // batch (128 blocks/batch)
    const int lane = tid & 63;
    const int wv   = tid >> 6;                      // 0..3
    const f16* Whi = (const f16*)Wswz;
    const f16* Wlo = Whi + WTOT;

    // ---- stage x into LDS ------------------------------------------------
    if (blk0) {
        float* Hf = (float*)s.H;                    // W(768) p(48)@768 m(48)@816
        const int ptbase = blockIdx.x * 16;
        for (int i = tid; i < 768; i += 256) Hf[i] = fcW[i];
        if (tid < 96) Hf[768 + tid] = (tid < 48) ? pts[ptbase*3 + tid]
                                                 : m_buf[ptbase*3 + tid - 48];
        __syncthreads();
#pragma unroll 1
        for (int it = 0; it < 6; ++it) {
            int idx = tid + 256*it;                 // 0..1535
            int r = idx >> 5;                       // j-row 0..47
            int cg = idx & 31;
            int l = r / 3, v = r - l*3;
            float pv0[3] = {Hf[768+l*3], Hf[768+l*3+1], Hf[768+l*3+2]};
            float mv0[3] = {Hf[816+l*3], Hf[816+l*3+1], Hf[816+l*3+2]};
            int v1 = (v==2) ? 0 : v+1;
            int v2 = (v==0) ? 2 : v-1;
            float av = mv0[v] - pv0[v];
            float bv = pv0[v];
            float cv = mv0[v1]*pv0[v2] - mv0[v2]*pv0[v1];
            half8 o;
#pragma unroll
            for (int k = 0; k < 8; ++k) {
                int ch = cg*8 + k;
                o[k] = (f16)(Hf[ch*3+0]*av + Hf[ch*3+1]*bv + Hf[ch*3+2]*cv);
            }
            *(half8*)&s.X[r*264 + cg*8] = o;
        }
    } else {
#pragma unroll 1
        for (int it = 0; it < 6; ++it) {
            int idx = tid + 256*it;
            int r = idx >> 5;
            int cg = idx & 31;
            if (cg < 16) {
                uint4 vv = *(const uint4*)(netIn + (size_t)(jb + r)*128 + cg*8);
                *(uint4*)&s.X[r*264 + cg*8] = vv;
            } else {
                int v = r % 3;                      // jb % 3 == 0
                const float* np = nm_prev + (bB*3+v)*128 + (cg-16)*8;
                half8 o;
#pragma unroll
                for (int k = 0; k < 8; ++k) o[k] = (f16)(np[k] * (1.0f/2048.0f));
                *(half8*)&s.X[r*264 + cg*8] = o;
            }
        }
    }
    __syncthreads();

    // ---- gemm1: d = D0 @ x (M=256, K=256), hi-only -----------------------
    {
        floatx4 acc[4][3];
#pragma unroll
        for (int a = 0; a < 4; ++a)
#pragma unroll
            for (int b = 0; b < 3; ++b) acc[a][b] = (floatx4){0,0,0,0};
        run_gemm_hi<4,3,8>(Whi, (size_t)offD0 + (size_t)wv*16384, s.X, 264, lane, acc);
#pragma unroll
        for (int fm = 0; fm < 4; ++fm)
#pragma unroll
            for (int fj = 0; fj < 3; ++fj) {
                int mloc = wv*64 + fm*16 + (lane>>4)*4;
                int jl   = fj*16 + (lane & 15);
                *(uint2*)&s.Y.d[jl*264 + mloc] = pack_hi(acc[fm][fj]);
            }
    }
    __syncthreads();

    // ---- relu1: y = vnrelu(x, d), width 256, in-place in Y ---------------
#pragma unroll 1
    for (int it = 0; it < 2; ++it) {
        int idx = tid + 256*it;
        int l = idx >> 5, cg = idx & 31;
        half8 xa = *(const half8*)&s.X[(l*3+0)*264 + cg*8];
        half8 xb = *(const half8*)&s.X[(l*3+1)*264 + cg*8];
        half8 xc = *(const half8*)&s.X[(l*3+2)*264 + cg*8];
        half8 da = *(const half8*)&s.Y.d[(l*3+0)*264 + cg*8];
        half8 db = *(const half8*)&s.Y.d[(l*3+1)*264 + cg*8];
        half8 dc = *(const half8*)&s.Y.d[(l*3+2)*264 + cg*8];
        half8 ya, yb, yc;
#pragma unroll
        for (int k = 0; k < 8; ++k) {
            float x0 = (float)xa[k], x1 = (float)xb[k], x2 = (float)xc[k];
            float d0 = (float)da[k], d1 = (float)db[k], d2 = (float)dc[k];
            float dot = x0*d0 + x1*d1 + x2*d2;
            float y0, y1, y2;
            if (dot >= 0.f) { y0 = x0; y1 = x1; y2 = x2; }
            else {
                float dsq = d0*d0 + d1*d1 + d2*d2 + 1e-8f;
                float sc = dot / dsq;
                y0 = x0 - sc*d0; y1 = x1 - sc*d1; y2 = x2 - sc*d2;
            }
            ya[k] = (f16)y0; yb[k] = (f16)y1; yc[k] = (f16)y2;
        }
        *(half8*)&s.Y.d[(l*3+0)*264 + cg*8] = ya;
        *(half8*)&s.Y.d[(l*3+1)*264 + cg*8] = yb;
        *(half8*)&s.Y.d[(l*3+2)*264 + cg*8] = yc;
    }
    __syncthreads();

    // ---- gemm2: h = W0 @ y (M=128, K=256), split -------------------------
    {
        floatx4 acc[2][3], accL[2][3];
#pragma unroll
        for (int a = 0; a < 2; ++a)
#pragma unroll
            for (int b = 0; b < 3; ++b) { acc[a][b] = (floatx4){0,0,0,0}; accL[a][b] = (floatx4){0,0,0,0}; }
        run_gemm_split<2,3,8>(Whi, Wlo, (size_t)offW0 + (size_t)wv*8192, s.Y.d, 264, lane, acc, accL);
#pragma unroll
        for (int fm = 0; fm < 2; ++fm)
#pragma unroll
            for (int fj = 0; fj < 3; ++fj) {
                int mloc = wv*32 + fm*16 + (lane>>4)*4;
                int jl   = fj*16 + (lane & 15);
                *(uint2*)&s.H[jl*136 + mloc] = pack_res(acc[fm][fj], accL[fm][fj]);
            }
    }
    __syncthreads();

    // ---- gemm3: d1 = D1 @ h (M=128, K=128), hi-only -> Y stride 136 ------
    {
        floatx4 acc[2][3];
#pragma unroll
        for (int a = 0; a < 2; ++a)
#pragma unroll
            for (int b = 0; b < 3; ++b) acc[a][b] = (floatx4){0,0,0,0};
        run_gemm_hi<2,3,4>(Whi, (size_t)offD1 + (size_t)wv*4096, s.H, 136, lane, acc);
#pragma unroll
        for (int fm = 0; fm < 2; ++fm)
#pragma unroll
            for (int fj = 0; fj < 3; ++fj) {
                int mloc = wv*32 + fm*16 + (lane>>4)*4;
                int jl   = fj*16 + (lane & 15);
                *(uint2*)&s.Y.d[jl*136 + mloc] = pack_hi(acc[fm][fj]);
            }
    }
    __syncthreads();

    // ---- relu2: y2 = vnrelu(h, d1), width 128, write over H --------------
    {
        int l = tid >> 4, cg = tid & 15;
        half8 xa = *(const half8*)&s.H[(l*3+0)*136 + cg*8];
        half8 xb = *(const half8*)&s.H[(l*3+1)*136 + cg*8];
        half8 xc = *(const half8*)&s.H[(l*3+2)*136 + cg*8];
        half8 da = *(const half8*)&s.Y.d[(l*3+0)*136 + cg*8];
        half8 db = *(const half8*)&s.Y.d[(l*3+1)*136 + cg*8];
        half8 dc = *(const half8*)&s.Y.d[(l*3+2)*136 + cg*8];
        half8 ya, yb, yc;
#pragma unroll
        for (int k = 0; k < 8; ++k) {
            float x0 = (float)xa[k], x1 = (float)xb[k], x2 = (float)xc[k];
            float d0 = (float)da[k], d1 = (float)db[k], d2 = (float)dc[k];
            float dot = x0*d0 + x1*d1 + x2*d2;
            float y0, y1, y2;
            if (dot >= 0.f) { y0 = x0; y1 = x1; y2 = x2; }
            else {
                float dsq = d0*d0 + d1*d1 + d2*d2 + 1e-8f;
                float sc = dot / dsq;
                y0 = x0 - sc*d0; y1 = x1 - sc*d1; y2 = x2 - sc*d2;
            }
            ya[k] = (f16)y0; yb[k] = (f16)y1; yc[k] = (f16)y2;
        }
        __syncthreads();
        *(half8*)&s.H[(l*3+0)*136 + cg*8] = ya;
        *(half8*)&s.H[(l*3+1)*136 + cg*8] = yb;
        *(half8*)&s.H[(l*3+2)*136 + cg*8] = yc;
    }
    __syncthreads();

    // ---- gemm4: net = Ws@x + W1@y2 (split), store + fused pool -----------
    {
        floatx4 acc[2][3], accL[2][3];
#pragma unroll
        for (int a = 0; a < 2; ++a)
#pragma unroll
            for (int b = 0; b < 3; ++b) { acc[a][b] = (floatx4){0,0,0,0}; accL[a][b] = (floatx4){0,0,0,0}; }
        run_gemm_split<2,3,8>(Whi, Wlo, (size_t)offWs + (size_t)wv*8192, s.X, 264, lane, acc, accL);
        run_gemm_split<2,3,4>(Whi, Wlo, (size_t)offW1 + (size_t)wv*4096, s.H, 136, lane, acc, accL);
#pragma unroll
        for (int fm = 0; fm < 2; ++fm)
#pragma unroll
            for (int fj = 0; fj < 3; ++fj) {
                int mloc = wv*32 + fm*16 + (lane>>4)*4;
                int jl   = fj*16 + (lane & 15);
                floatx4 res;
#pragma unroll
                for (int r = 0; r < 4; ++r) res[r] = acc[fm][fj][r] + accL[fm][fj][r] * (1.0f/1024.0f);
                if (!do_head) {
                    u16 hh[4];
#pragma unroll
                    for (int r = 0; r < 4; ++r) { f16 hv = (f16)res[r]; hh[r] = *(u16*)&hv; }
                    uint2 pv;
                    pv.x = (u32)hh[0] | ((u32)hh[1] << 16);
                    pv.y = (u32)hh[2] | ((u32)hh[3] << 16);
                    *(uint2*)(netOut + (size_t)(jb + jl)*128 + mloc) = pv;
                }
                *(floatx4*)&s.Y.C[jl*132 + mloc] = res;
            }
    }
    __syncthreads();

    // ---- pool: sum over 16 points per (v, ch), atomic into nm_out --------
#pragma unroll 1
    for (int idx = tid; idx < 384; idx += 256) {
        int v = idx >> 7, ch = idx & 127;
        float sum = 0.f;
#pragma unroll 1
        for (int pt = 0; pt < 16; ++pt) sum += s.Y.C[(pt*3+v)*132 + ch];
        atomicAdd(nm_out + (bB*3+v)*128 + ch, sum);
    }

    // ---- fused final head: last-arriving block only ----------------------
    if (do_head) {
        __threadfence();
        if (tid == 0) lastFlag = (atomicAdd(sync_cnt, 1) == 511) ? 1 : 0;
        __syncthreads();
        if (lastFlag) {
            __threadfence();
            float* xs = (float*)&s.X[0];            // [2][384]
            float* ys = xs + 768;                   // [2][384]
            const int c = tid & 127;
            const int half = tid >> 7;
            float* nm_sum = nm_out;
#pragma unroll 1
            for (int rep = 0; rep < 2; ++rep) {
                int b = half + rep*2;
                float* x = xs + half*384;
                float* y = ys + half*384;
                // atomic loads: coherent across XCDs
                x[c*3+0] = atomicAdd(&nm_sum[(b*3+0)*128 + c], 0.0f) * (1.0f/2048.0f);
                x[c*3+1] = atomicAdd(&nm_sum[(b*3+1)*128 + c], 0.0f) * (1.0f/2048.0f);
                x[c*3+2] = atomicAdd(&nm_sum[(b*3+2)*128 + c], 0.0f) * (1.0f/2048.0f);
                __syncthreads();
                float d0 = 0.f, d1 = 0.f, d2 = 0.f;
                for (int i = 0; i < 128; ++i) {
                    float w = act_d[c*128 + i];
                    d0 = fmaf(w, x[i*3+0], d0);
                    d1 = fmaf(w, x[i*3+1], d1);
                    d2 = fmaf(w, x[i*3+2], d2);
                }
                float x0 = x[c*3+0], x1 = x[c*3+1], x2 = x[c*3+2];
                float dot = x0*d0 + x1*d1 + x2*d2;
                float y0, y1, y2;
                if (dot >= 0.f) { y0 = x0; y1 = x1; y2 = x2; }
                else {
                    float dsq = d0*d0 + d1*d1 + d2*d2 + 1e-8f;
                    float sc = dot / dsq;
                    y0 = x0 - sc*d0; y1 = x1 - sc*d1; y2 = x2 - sc*d2;
                }
                y[c*3+0] = y0; y[c*3+1] = y1; y[c*3+2] = y2;
                __syncthreads();
                float o0 = 0.f, o1 = 0.f, o2 = 0.f;
                for (int i = 0; i < 128; ++i) {
                    float w = fc_c[c*128 + i];
                    o0 = fmaf(w, y[i*3+0], o0);
                    o1 = fmaf(w, y[i*3+1], o1);
                    o2 = fmaf(w, y[i*3+2], o2);
                }
                out[b*384 + c*3 + 0] = o0;
                out[b*384 + c*3 + 1] = o1;
                out[b*384 + c*3 + 2] = o2;
                __syncthreads();
            }
        }
    }
}

// ---------------------------------------------------------------------------
extern "C" void kernel_launch(void* const* d_in, const int* in_sizes, int n_in,
                              void* d_out, int out_size, void* d_ws, size_t ws_size,
                              hipStream_t stream)
{
    const float* p      = (const float*)d_in[0];
    const float* fc_pos = (const float*)d_in[1];
    const float* bd0    = (const float*)d_in[2];
    const float* bW0    = (const float*)d_in[3];
    const float* bd1    = (const float*)d_in[4];
    const float* bW1    = (const float*)d_in[5];
    const float* bWs    = (const float*)d_in[6];
    const float* fc_c   = (const float*)d_in[7];
    const float* act_d  = (const float*)d_in[8];
    float* out = (float*)d_out;

    // Workspace layout (16B-aligned)
    char* w = (char*)d_ws;
    float* m_buf    = (float*)w;  w += 98304;                // knn means
    float* nm_acc   = (float*)w;  w += 5*1536*4;             // pool sums
    int*   sync_cnt = (int*)w;    w += 16;
    u16*   Wswz     = (u16*)w;    w += (size_t)2*WTOT*2;     // swizzled split weights
    f16*   netA     = (f16*)w;    w += (size_t)24576*128*2;
    f16*   netB     = (f16*)w;    w += (size_t)24576*128*2;

    prep_kernel<<<dim3(1024 + 3200), dim3(256), 0, stream>>>(
        p, m_buf, bd0, bW0, bd1, bW1, bWs, Wswz, nm_acc, sync_cnt);

    f16* nIn = netA;
    f16* nOut = netB;
    for (int blk = 0; blk < 5; ++blk) {
        const int offD0 = blk*65536;
        const int offW0 = 327680 + blk*32768;
        const int offD1 = 491520 + blk*16384;
        const int offW1 = 573440 + blk*16384;
        const int offWs = 655360 + blk*32768;
        const float* nmp = (blk == 0) ? nullptr : (nm_acc + (blk-1)*1536);
        resblk_kernel<<<dim3(512), dim3(256), 0, stream>>>(
            Wswz, offD0, offW0, offD1, offW1, offWs,
            (blk == 0) ? netA : nIn, nmp, p, m_buf, fc_pos,
            nOut, nm_acc + blk*1536, (blk == 0) ? 1 : 0,
            (blk == 4) ? 1 : 0, sync_cnt, act_d, fc_c, out);
        f16* tmp = nIn; nIn = nOut; nOut = tmp;
    }

    (void)in_sizes; (void)n_in; (void)out_size; (void)ws_size;
}

// Round 12
// 283.188 us; speedup vs baseline: 1.0114x; 1.0114x over previous
//
#include <hip/hip_runtime.h>
#include <math.h>

#define N_PTS 2048
#define K_NN  20
#define K_D   10              // per-slice kept depth
#define WTOT  819200          // total weight elements across the 5 tensors

typedef unsigned short u16;
typedef unsigned int   u32;
typedef _Float16 f16;
using half8   = __attribute__((ext_vector_type(8))) _Float16;
using floatx4 = __attribute__((ext_vector_type(4))) float;

// Weights: split fp16.  w ~= hi + lo/1024, |err| ~ 2^-24 |w|.
__device__ __forceinline__ void split2h(float v, f16& h, f16& l) {
    h = (f16)v;
    l = (f16)((v - (float)h) * 1024.0f);
}

// nd must be bit-identical in phase 1 and phase 2b.
__device__ __forceinline__ float neg_dist(float4 q2, float4 c) {
    return fmaf(q2.x, c.x, fmaf(q2.y, c.y, fmaf(q2.z, c.z, -q2.w))) - c.w;
}

// ---------------------------------------------------------------------------
// prep_kernel = KNN (blocks 0..1023) + weight convert/swizzle (blocks 1024+).
// Also zeroes nm_acc and the head sync counter every launch (replay-safe).
// ---------------------------------------------------------------------------
__global__ __launch_bounds__(256) void prep_kernel(
    const float* __restrict__ pts, float* __restrict__ m_out,
    const float* __restrict__ bd0, const float* __restrict__ bW0,
    const float* __restrict__ bd1, const float* __restrict__ bW1,
    const float* __restrict__ bWs, u16* __restrict__ Wswz,
    float* __restrict__ nm_acc, int* __restrict__ sync_cnt)
{
    __shared__ float4 sp[N_PTS];                      // 32 KB (knn branch only)
    if (blockIdx.x >= 1024) {
        int i = (blockIdx.x - 1024) * 256 + threadIdx.x;
        if (i >= WTOT) return;
        if (i < 7680) nm_acc[i] = 0.f;
        if (i == 0) sync_cnt[0] = 0;
        float v; int base, K, local;
        if (i < 327680)      { int rel = i;          base = (rel/65536)*65536;            local = rel%65536; K = 256; v = bd0[rel]; }
        else if (i < 491520) { int rel = i - 327680; base = 327680 + (rel/32768)*32768;   local = rel%32768; K = 256; v = bW0[rel]; }
        else if (i < 573440) { int rel = i - 491520; base = 491520 + (rel/16384)*16384;   local = rel%16384; K = 128; v = bd1[rel]; }
        else if (i < 655360) { int rel = i - 573440; base = 573440 + (rel/16384)*16384;   local = rel%16384; K = 128; v = bW1[rel]; }
        else                 { int rel = i - 655360; base = 655360 + (rel/32768)*32768;   local = rel%32768; K = 256; v = bWs[rel]; }
        int m = local / K, k = local % K;
        int NKF = K >> 5;
        int mf = m >> 4, r = m & 15;
        int kf = k >> 5, q = (k >> 3) & 3, ii = k & 7;
        int lane = q*16 + r;
        int dst = base + ((mf*NKF + kf)*64 + lane)*8 + ii;
        f16 h, l; split2h(v, h, l);
        f16* W = (f16*)Wswz;
        W[dst] = h; W[WTOT + dst] = l;
        return;
    }

    // ---- KNN ----
    const int b     = blockIdx.x >> 8;
    const int qbase = (blockIdx.x & 255) << 3;
    const int ql    = threadIdx.x >> 5;
    const int sl    = threadIdx.x & 31;
    const float* pb = pts + (size_t)b * N_PTS * 3;
    for (int i = threadIdx.x; i < N_PTS; i += 256) {
        float x = pb[i*3+0], y = pb[i*3+1], z = pb[i*3+2];
        sp[i] = make_float4(x, y, z, x*x + y*y + z*z);
    }
    __syncthreads();

    const int n = qbase + ql;
    const float4 q = sp[n];
    const float4 q2 = make_float4(2.f*q.x, 2.f*q.y, 2.f*q.z, q.w);

    float t[K_D];
#pragma unroll
    for (int s = 0; s < K_D; ++s) t[s] = -INFINITY;

    for (int j = 0; j < N_PTS/32; ++j) {
        float4 c = sp[j*32 + sl];
        float v = neg_dist(q2, c);
#pragma unroll
        for (int s = 0; s < K_D; ++s) {
            float nx = (s < K_D-1) ? t[s+1] : INFINITY;
            t[s] = fminf(fmaxf(t[s], v), nx);
        }
    }

    float head = t[K_D-1];
    float T = -INFINITY;
#pragma unroll 1
    for (int e = 0; e < K_NN; ++e) {
        float v = head; int w = sl;
#pragma unroll
        for (int off = 1; off < 32; off <<= 1) {
            float vo = __shfl_xor(v, off);
            int   wo = __shfl_xor(w, off);
            bool take = (vo > v) || (vo == v && wo < w);
            v = take ? vo : v;
            w = take ? wo : w;
        }
        T = v;
        if (w == sl) {
#pragma unroll
            for (int s = K_D-1; s > 0; --s) t[s] = t[s-1];
            t[0] = -INFINITY;
            head = t[K_D-1];
        }
    }

    float sx = 0.f, sy = 0.f, sz = 0.f;
    for (int j = 0; j < N_PTS/32; ++j) {
        float4 c = sp[j*32 + sl];
        float v = neg_dist(q2, c);
        if (v >= T) { sx += c.x; sy += c.y; sz += c.z; }
    }
#pragma unroll
    for (int off = 1; off < 32; off <<= 1) {
        sx += __shfl_xor(sx, off);
        sy += __shfl_xor(sy, off);
        sz += __shfl_xor(sz, off);
    }
    if (sl == 0) {
        const float inv = 1.0f / (float)K_NN;
        const int pt = b * N_PTS + n;
        m_out[pt*3+0] = sx * inv;
        m_out[pt*3+1] = sy * inv;
        m_out[pt*3+2] = sz * inv;
    }
}

// ---------------------------------------------------------------------------
// MFMA GEMM cores (round-9 measured-good form): runtime NK, compact
// `#pragma unroll 1` kf-loop, Aa/Ab ping-pong (depth-1 overlap).
// A-frags from L2 (swizzled), B from LDS.
// ---------------------------------------------------------------------------
template<int MF, int JF>
__device__ __forceinline__ void run_gemm_hi(
    const f16* __restrict__ Whi, size_t aoff,
    int NK, const f16* Blds, int bstride, int lane,
    floatx4 (&acc)[MF][JF])
{
    const int l15 = lane & 15;
    const int lq8 = (lane >> 4) * 8;
    half8 Aa[MF], Ab[MF];

    auto loada = [&](half8 (&dst)[MF], int kf) {
#pragma unroll
        for (int fm = 0; fm < MF; ++fm)
            dst[fm] = *(const half8*)(Whi + aoff + (size_t)(fm*NK + kf)*512 + (size_t)lane*8);
    };
    auto step = [&](half8 (&af)[MF], int kf) {
        half8 bq[JF];
#pragma unroll
        for (int fj = 0; fj < JF; ++fj)
            bq[fj] = *(const half8*)&Blds[(fj*16 + l15)*bstride + kf*32 + lq8];
#pragma unroll
        for (int fm = 0; fm < MF; ++fm)
#pragma unroll
            for (int fj = 0; fj < JF; ++fj)
                acc[fm][fj] = __builtin_amdgcn_mfma_f32_16x16x32_f16(af[fm], bq[fj], acc[fm][fj], 0, 0, 0);
    };

    loada(Aa, 0);
#pragma unroll 1
    for (int kf = 0; kf < NK; kf += 2) {
        loada(Ab, kf + 1);
        step(Aa, kf);
        if (kf + 2 < NK) loada(Aa, kf + 2);
        step(Ab, kf + 1);
    }
}

template<int MF, int JF>
__device__ __forceinline__ void run_gemm_split(
    const f16* __restrict__ Whi, const f16* __restrict__ Wlo, size_t aoff,
    int NK, const f16* Blds, int bstride, int lane,
    floatx4 (&acc)[MF][JF], floatx4 (&accL)[MF][JF])
{
    const int l15 = lane & 15;
    const int lq8 = (lane >> 4) * 8;
    half8 Aa[2*MF], Ab[2*MF];

    auto loada = [&](half8 (&dst)[2*MF], int kf) {
#pragma unroll
        for (int fm = 0; fm < MF; ++fm) {
            size_t fo = aoff + (size_t)(fm*NK + kf)*512 + (size_t)lane*8;
            dst[fm*2+0] = *(const half8*)(Whi + fo);
            dst[fm*2+1] = *(const half8*)(Wlo + fo);
        }
    };
    auto step = [&](half8 (&af)[2*MF], int kf) {
        half8 bq[JF];
#pragma unroll
        for (int fj = 0; fj < JF; ++fj)
            bq[fj] = *(const half8*)&Blds[(fj*16 + l15)*bstride + kf*32 + lq8];
#pragma unroll
        for (int fm = 0; fm < MF; ++fm)
#pragma unroll
            for (int fj = 0; fj < JF; ++fj) {
                acc[fm][fj]  = __builtin_amdgcn_mfma_f32_16x16x32_f16(af[fm*2+0], bq[fj], acc[fm][fj], 0, 0, 0);
                accL[fm][fj] = __builtin_amdgcn_mfma_f32_16x16x32_f16(af[fm*2+1], bq[fj], accL[fm][fj], 0, 0, 0);
            }
    };

    loada(Aa, 0);
#pragma unroll 1
    for (int kf = 0; kf < NK; kf += 2) {
        loada(Ab, kf + 1);
        step(Aa, kf);
        if (kf + 2 < NK) loada(Aa, kf + 2);
        step(Ab, kf + 1);
    }
}

__device__ __forceinline__ uint2 pack_res(floatx4 a, floatx4 aL) {
    u16 hh[4];
#pragma unroll
    for (int r = 0; r < 4; ++r) {
        f16 hv = (f16)(a[r] + aL[r] * (1.0f/1024.0f));
        hh[r] = *(u16*)&hv;
    }
    uint2 pv;
    pv.x = (u32)hh[0] | ((u32)hh[1] << 16);
    pv.y = (u32)hh[2] | ((u32)hh[3] << 16);
    return pv;
}

__device__ __forceinline__ uint2 pack_hi(floatx4 a) {
    u16 hh[4];
#pragma unroll
    for (int r = 0; r < 4; ++r) {
        f16 hv = (f16)a[r];
        hh[r] = *(u16*)&hv;
    }
    uint2 pv;
    pv.x = (u32)hh[0] | ((u32)hh[1] << 16);
    pv.y = (u32)hh[2] | ((u32)hh[3] << 16);
    return pv;
}

// ---------------------------------------------------------------------------
// Fused resnet block (round-9 structure, verified) + fused final head.
// do_head: last-arriving block (atomic counter) runs the head; pool sums are
// read back with atomic loads (device-coherent). blk4 skips netOut stores.
// ---------------------------------------------------------------------------
__global__ __launch_bounds__(256, 2) void resblk_kernel(
    const u16* __restrict__ Wswz,
    int offD0, int offW0, int offD1, int offW1, int offWs,
    const f16* __restrict__ netIn, const float* __restrict__ nm_prev,
    const float* __restrict__ pts, const float* __restrict__ m_buf,
    const float* __restrict__ fcW,
    f16* __restrict__ netOut, float* __restrict__ nm_out, int blk0,
    int do_head, int* __restrict__ sync_cnt,
    const float* __restrict__ act_d, const float* __restrict__ fc_c,
    float* __restrict__ out)
{
    __shared__ struct {
        f16 X[48*264];                              // x (width 256), 25344 B
        union { f16 d[48*264]; float C[48*132]; } Y;
        f16 H[48*136];                              // h / y2 (width 128)
    } s;
    __shared__ int lastFlag;

    const int tid  = threadIdx.x;
    const int jb   = blockIdx.x * 48;
    const int bB   = blockIdx.x >> 7;               // batch (128 blocks/batch)
    const int lane = tid & 63;
    const int wv   = tid >> 6;                      // 0..3
    const f16* Whi = (const f16*)Wswz;
    const f16* Wlo = Whi + WTOT;

    // ---- stage x into LDS ------------------------------------------------
    if (blk0) {
        float* Hf = (float*)s.H;                    // W(768) p(48)@768 m(48)@816
        const int ptbase = blockIdx.x * 16;
        for (int i = tid; i < 768; i += 256) Hf[i] = fcW[i];
        if (tid < 96) Hf[768 + tid] = (tid < 48) ? pts[ptbase*3 + tid]
                                                 : m_buf[ptbase*3 + tid - 48];
        __syncthreads();
#pragma unroll 1
        for (int it = 0; it < 6; ++it) {
            int idx = tid + 256*it;                 // 0..1535
            int r = idx >> 5;                       // j-row 0..47
            int cg = idx & 31;
            int l = r / 3, v = r - l*3;
            float pv0[3] = {Hf[768+l*3], Hf[768+l*3+1], Hf[768+l*3+2]};
            float mv0[3] = {Hf[816+l*3], Hf[816+l*3+1], Hf[816+l*3+2]};
            int v1 = (v==2) ? 0 : v+1;
            int v2 = (v==0) ? 2 : v-1;
            float av = mv0[v] - pv0[v];
            float bv = pv0[v];
            float cv = mv0[v1]*pv0[v2] - mv0[v2]*pv0[v1];
            half8 o;
#pragma unroll
            for (int k = 0; k < 8; ++k) {
                int ch = cg*8 + k;
                o[k] = (f16)(Hf[ch*3+0]*av + Hf[ch*3+1]*bv + Hf[ch*3+2]*cv);
            }
            *(half8*)&s.X[r*264 + cg*8] = o;
        }
    } else {
#pragma unroll 1
        for (int it = 0; it < 6; ++it) {
            int idx = tid + 256*it;
            int r = idx >> 5;
            int cg = idx & 31;
            if (cg < 16) {
                uint4 vv = *(const uint4*)(netIn + (size_t)(jb + r)*128 + cg*8);
                *(uint4*)&s.X[r*264 + cg*8] = vv;
            } else {
                int v = r % 3;                      // jb % 3 == 0
                const float* np = nm_prev + (bB*3+v)*128 + (cg-16)*8;
                half8 o;
#pragma unroll
                for (int k = 0; k < 8; ++k) o[k] = (f16)(np[k] * (1.0f/2048.0f));
                *(half8*)&s.X[r*264 + cg*8] = o;
            }
        }
    }
    __syncthreads();

    // ---- gemm1: d = D0 @ x (M=256, K=256), hi-only -----------------------
    {
        floatx4 acc[4][3];
#pragma unroll
        for (int a = 0; a < 4; ++a)
#pragma unroll
            for (int b = 0; b < 3; ++b) acc[a][b] = (floatx4){0,0,0,0};
        run_gemm_hi<4,3>(Whi, (size_t)offD0 + (size_t)wv*16384, 8, s.X, 264, lane, acc);
#pragma unroll
        for (int fm = 0; fm < 4; ++fm)
#pragma unroll
            for (int fj = 0; fj < 3; ++fj) {
                int mloc = wv*64 + fm*16 + (lane>>4)*4;
                int jl   = fj*16 + (lane & 15);
                *(uint2*)&s.Y.d[jl*264 + mloc] = pack_hi(acc[fm][fj]);
            }
    }
    __syncthreads();

    // ---- relu1: y = vnrelu(x, d), width 256, in-place in Y ---------------
#pragma unroll 1
    for (int it = 0; it < 2; ++it) {
        int idx = tid + 256*it;
        int l = idx >> 5, cg = idx & 31;
        half8 xa = *(const half8*)&s.X[(l*3+0)*264 + cg*8];
        half8 xb = *(const half8*)&s.X[(l*3+1)*264 + cg*8];
        half8 xc = *(const half8*)&s.X[(l*3+2)*264 + cg*8];
        half8 da = *(const half8*)&s.Y.d[(l*3+0)*264 + cg*8];
        half8 db = *(const half8*)&s.Y.d[(l*3+1)*264 + cg*8];
        half8 dc = *(const half8*)&s.Y.d[(l*3+2)*264 + cg*8];
        half8 ya, yb, yc;
#pragma unroll
        for (int k = 0; k < 8; ++k) {
            float x0 = (float)xa[k], x1 = (float)xb[k], x2 = (float)xc[k];
            float d0 = (float)da[k], d1 = (float)db[k], d2 = (float)dc[k];
            float dot = x0*d0 + x1*d1 + x2*d2;
            float y0, y1, y2;
            if (dot >= 0.f) { y0 = x0; y1 = x1; y2 = x2; }
            else {
                float dsq = d0*d0 + d1*d1 + d2*d2 + 1e-8f;
                float sc = dot / dsq;
                y0 = x0 - sc*d0; y1 = x1 - sc*d1; y2 = x2 - sc*d2;
            }
            ya[k] = (f16)y0; yb[k] = (f16)y1; yc[k] = (f16)y2;
        }
        *(half8*)&s.Y.d[(l*3+0)*264 + cg*8] = ya;
        *(half8*)&s.Y.d[(l*3+1)*264 + cg*8] = yb;
        *(half8*)&s.Y.d[(l*3+2)*264 + cg*8] = yc;
    }
    __syncthreads();

    // ---- gemm2: h = W0 @ y (M=128, K=256), split -------------------------
    {
        floatx4 acc[2][3], accL[2][3];
#pragma unroll
        for (int a = 0; a < 2; ++a)
#pragma unroll
            for (int b = 0; b < 3; ++b) { acc[a][b] = (floatx4){0,0,0,0}; accL[a][b] = (floatx4){0,0,0,0}; }
        run_gemm_split<2,3>(Whi, Wlo, (size_t)offW0 + (size_t)wv*8192, 8, s.Y.d, 264, lane, acc, accL);
#pragma unroll
        for (int fm = 0; fm < 2; ++fm)
#pragma unroll
            for (int fj = 0; fj < 3; ++fj) {
                int mloc = wv*32 + fm*16 + (lane>>4)*4;
                int jl   = fj*16 + (lane & 15);
                *(uint2*)&s.H[jl*136 + mloc] = pack_res(acc[fm][fj], accL[fm][fj]);
            }
    }
    __syncthreads();

    // ---- gemm3: d1 = D1 @ h (M=128, K=128), hi-only -> Y stride 136 ------
    {
        floatx4 acc[2][3];
#pragma unroll
        for (int a = 0; a < 2; ++a)
#pragma unroll
            for (int b = 0; b < 3; ++b) acc[a][b] = (floatx4){0,0,0,0};
        run_gemm_hi<2,3>(Whi, (size_t)offD1 + (size_t)wv*4096, 4, s.H, 136, lane, acc);
#pragma unroll
        for (int fm = 0; fm < 2; ++fm)
#pragma unroll
            for (int fj = 0; fj < 3; ++fj) {
                int mloc = wv*32 + fm*16 + (lane>>4)*4;
                int jl   = fj*16 + (lane & 15);
                *(uint2*)&s.Y.d[jl*136 + mloc] = pack_hi(acc[fm][fj]);
            }
    }
    __syncthreads();

    // ---- relu2: y2 = vnrelu(h, d1), width 128, write over H --------------
    {
        int l = tid >> 4, cg = tid & 15;
        half8 xa = *(const half8*)&s.H[(l*3+0)*136 + cg*8];
        half8 xb = *(const half8*)&s.H[(l*3+1)*136 + cg*8];
        half8 xc = *(const half8*)&s.H[(l*3+2)*136 + cg*8];
        half8 da = *(const half8*)&s.Y.d[(l*3+0)*136 + cg*8];
        half8 db = *(const half8*)&s.Y.d[(l*3+1)*136 + cg*8];
        half8 dc = *(const half8*)&s.Y.d[(l*3+2)*136 + cg*8];
        half8 ya, yb, yc;
#pragma unroll
        for (int k = 0; k < 8; ++k) {
            float x0 = (float)xa[k], x1 = (float)xb[k], x2 = (float)xc[k];
            float d0 = (float)da[k], d1 = (float)db[k], d2 = (float)dc[k];
            float dot = x0*d0 + x1*d1 + x2*d2;
            float y0, y1, y2;
            if (dot >= 0.f) { y0 = x0; y1 = x1; y2 = x2; }
            else {
                float dsq = d0*d0 + d1*d1 + d2*d2 + 1e-8f;
                float sc = dot / dsq;
                y0 = x0 - sc*d0; y1 = x1 - sc*d1; y2 = x2 - sc*d2;
            }
            ya[k] = (f16)y0; yb[k] = (f16)y1; yc[k] = (f16)y2;
        }
        __syncthreads();
        *(half8*)&s.H[(l*3+0)*136 + cg*8] = ya;
        *(half8*)&s.H[(l*3+1)*136 + cg*8] = yb;
        *(half8*)&s.H[(l*3+2)*136 + cg*8] = yc;
    }
    __syncthreads();

    // ---- gemm4: net = Ws@x + W1@y2 (split), store + fused pool -----------
    {
        floatx4 acc[2][3], accL[2][3];
#pragma unroll
        for (int a = 0; a < 2; ++a)
#pragma unroll
            for (int b = 0; b < 3; ++b) { acc[a][b] = (floatx4){0,0,0,0}; accL[a][b] = (floatx4){0,0,0,0}; }
        run_gemm_split<2,3>(Whi, Wlo, (size_t)offWs + (size_t)wv*8192, 8, s.X, 264, lane, acc, accL);
        run_gemm_split<2,3>(Whi, Wlo, (size_t)offW1 + (size_t)wv*4096, 4, s.H, 136, lane, acc, accL);
#pragma unroll
        for (int fm = 0; fm < 2; ++fm)
#pragma unroll
            for (int fj = 0; fj < 3; ++fj) {
                int mloc = wv*32 + fm*16 + (lane>>4)*4;
                int jl   = fj*16 + (lane & 15);
                floatx4 res;
#pragma unroll
                for (int r = 0; r < 4; ++r) res[r] = acc[fm][fj][r] + accL[fm][fj][r] * (1.0f/1024.0f);
                if (!do_head) {
                    u16 hh[4];
#pragma unroll
                    for (int r = 0; r < 4; ++r) { f16 hv = (f16)res[r]; hh[r] = *(u16*)&hv; }
                    uint2 pv;
                    pv.x = (u32)hh[0] | ((u32)hh[1] << 16);
                    pv.y = (u32)hh[2] | ((u32)hh[3] << 16);
                    *(uint2*)(netOut + (size_t)(jb + jl)*128 + mloc) = pv;
                }
                *(floatx4*)&s.Y.C[jl*132 + mloc] = res;
            }
    }
    __syncthreads();

    // ---- pool: sum over 16 points per (v, ch), atomic into nm_out --------
#pragma unroll 1
    for (int idx = tid; idx < 384; idx += 256) {
        int v = idx >> 7, ch = idx & 127;
        float sum = 0.f;
#pragma unroll 1
        for (int pt = 0; pt < 16; ++pt) sum += s.Y.C[(pt*3+v)*132 + ch];
        atomicAdd(nm_out + (bB*3+v)*128 + ch, sum);
    }

    // ---- fused final head: last-arriving block only ----------------------
    if (do_head) {
        __threadfence();
        if (tid == 0) lastFlag = (atomicAdd(sync_cnt, 1) == 511) ? 1 : 0;
        __syncthreads();
        if (lastFlag) {
            __threadfence();
            float* xs = (float*)&s.X[0];            // [2][384]
            float* ys = xs + 768;                   // [2][384]
            const int c = tid & 127;
            const int half = tid >> 7;
            float* nm_sum = nm_out;
#pragma unroll 1
            for (int rep = 0; rep < 2; ++rep) {
                int b = half + rep*2;
                float* x = xs + half*384;
                float* y = ys + half*384;
                // atomic loads: coherent across XCDs
                x[c*3+0] = atomicAdd(&nm_sum[(b*3+0)*128 + c], 0.0f) * (1.0f/2048.0f);
                x[c*3+1] = atomicAdd(&nm_sum[(b*3+1)*128 + c], 0.0f) * (1.0f/2048.0f);
                x[c*3+2] = atomicAdd(&nm_sum[(b*3+2)*128 + c], 0.0f) * (1.0f/2048.0f);
                __syncthreads();
                float d0 = 0.f, d1 = 0.f, d2 = 0.f;
                for (int i = 0; i < 128; ++i) {
                    float w = act_d[c*128 + i];
                    d0 = fmaf(w, x[i*3+0], d0);
                    d1 = fmaf(w, x[i*3+1], d1);
                    d2 = fmaf(w, x[i*3+2], d2);
                }
                float x0 = x[c*3+0], x1 = x[c*3+1], x2 = x[c*3+2];
                float dot = x0*d0 + x1*d1 + x2*d2;
                float y0, y1, y2;
                if (dot >= 0.f) { y0 = x0; y1 = x1; y2 = x2; }
                else {
                    float dsq = d0*d0 + d1*d1 + d2*d2 + 1e-8f;
                    float sc = dot / dsq;
                    y0 = x0 - sc*d0; y1 = x1 - sc*d1; y2 = x2 - sc*d2;
                }
                y[c*3+0] = y0; y[c*3+1] = y1; y[c*3+2] = y2;
                __syncthreads();
                float o0 = 0.f, o1 = 0.f, o2 = 0.f;
                for (int i = 0; i < 128; ++i) {
                    float w = fc_c[c*128 + i];
                    o0 = fmaf(w, y[i*3+0], o0);
                    o1 = fmaf(w, y[i*3+1], o1);
                    o2 = fmaf(w, y[i*3+2], o2);
                }
                out[b*384 + c*3 + 0] = o0;
                out[b*384 + c*3 + 1] = o1;
                out[b*384 + c*3 + 2] = o2;
                __syncthreads();
            }
        }
    }
}

// ---------------------------------------------------------------------------
extern "C" void kernel_launch(void* const* d_in, const int* in_sizes, int n_in,
                              void* d_out, int out_size, void* d_ws, size_t ws_size,
                              hipStream_t stream)
{
    const float* p      = (const float*)d_in[0];
    const float* fc_pos = (const float*)d_in[1];
    const float* bd0    = (const float*)d_in[2];
    const float* bW0    = (const float*)d_in[3];
    const float* bd1    = (const float*)d_in[4];
    const float* bW1    = (const float*)d_in[5];
    const float* bWs    = (const float*)d_in[6];
    const float* fc_c   = (const float*)d_in[7];
    const float* act_d  = (const float*)d_in[8];
    float* out = (float*)d_out;

    // Workspace layout (16B-aligned)
    char* w = (char*)d_ws;
    float* m_buf    = (float*)w;  w += 98304;                // knn means
    float* nm_acc   = (float*)w;  w += 5*1536*4;             // pool sums
    int*   sync_cnt = (int*)w;    w += 16;
    u16*   Wswz     = (u16*)w;    w += (size_t)2*WTOT*2;     // swizzled split weights
    f16*   netA     = (f16*)w;    w += (size_t)24576*128*2;
    f16*   netB     = (f16*)w;    w += (size_t)24576*128*2;

    prep_kernel<<<dim3(1024 + 3200), dim3(256), 0, stream>>>(
        p, m_buf, bd0, bW0, bd1, bW1, bWs, Wswz, nm_acc, sync_cnt);

    f16* nIn = netA;
    f16* nOut = netB;
    for (int blk = 0; blk < 5; ++blk) {
        const int offD0 = blk*65536;
        const int offW0 = 327680 + blk*32768;
        const int offD1 = 491520 + blk*16384;
        const int offW1 = 573440 + blk*16384;
        const int offWs = 655360 + blk*32768;
        const float* nmp = (blk == 0) ? nullptr : (nm_acc + (blk-1)*1536);
        resblk_kernel<<<dim3(512), dim3(256), 0, stream>>>(
            Wswz, offD0, offW0, offD1, offW1, offWs,
            (blk == 0) ? netA : nIn, nmp, p, m_buf, fc_pos,
            nOut, nm_acc + blk*1536, (blk == 0) ? 1 : 0,
            (blk == 4) ? 1 : 0, sync_cnt, act_d, fc_c, out);
        f16* tmp = nIn; nIn = nOut; nOut = tmp;
    }

    (void)in_sizes; (void)n_in; (void)out_size; (void)ws_size;
}

// Round 13
// 241.209 us; speedup vs baseline: 1.1875x; 1.1740x over previous
//
#include <hip/hip_runtime.h>
#include <math.h>

#define N_PTS 2048
#define K_NN  20
#define K_D   10              // per-slice kept depth
#define WTOT  819200          // total weight elements across the 5 tensors

typedef unsigned short u16;
typedef unsigned int   u32;
typedef _Float16 f16;
using half8   = __attribute__((ext_vector_type(8))) _Float16;
using floatx4 = __attribute__((ext_vector_type(4))) float;

// Weights: split fp16.  w ~= hi + lo/1024, |err| ~ 2^-24 |w|.
__device__ __forceinline__ void split2h(float v, f16& h, f16& l) {
    h = (f16)v;
    l = (f16)((v - (float)h) * 1024.0f);
}

// nd must be bit-identical in phase 1 and phase 2b.
__device__ __forceinline__ float neg_dist(float4 q2, float4 c) {
    return fmaf(q2.x, c.x, fmaf(q2.y, c.y, fmaf(q2.z, c.z, -q2.w))) - c.w;
}

// ---------------------------------------------------------------------------
// prep_kernel = KNN (blocks 0..1023) + weight convert/swizzle (blocks 1024+).
// Also zeroes nm_acc every launch (replay-safe).
// ---------------------------------------------------------------------------
__global__ __launch_bounds__(256) void prep_kernel(
    const float* __restrict__ pts, float* __restrict__ m_out,
    const float* __restrict__ bd0, const float* __restrict__ bW0,
    const float* __restrict__ bd1, const float* __restrict__ bW1,
    const float* __restrict__ bWs, u16* __restrict__ Wswz,
    float* __restrict__ nm_acc)
{
    __shared__ float4 sp[N_PTS];                      // 32 KB (knn branch only)
    if (blockIdx.x >= 1024) {
        int i = (blockIdx.x - 1024) * 256 + threadIdx.x;
        if (i >= WTOT) return;
        if (i < 7680) nm_acc[i] = 0.f;
        float v; int base, K, local;
        if (i < 327680)      { int rel = i;          base = (rel/65536)*65536;            local = rel%65536; K = 256; v = bd0[rel]; }
        else if (i < 491520) { int rel = i - 327680; base = 327680 + (rel/32768)*32768;   local = rel%32768; K = 256; v = bW0[rel]; }
        else if (i < 573440) { int rel = i - 491520; base = 491520 + (rel/16384)*16384;   local = rel%16384; K = 128; v = bd1[rel]; }
        else if (i < 655360) { int rel = i - 573440; base = 573440 + (rel/16384)*16384;   local = rel%16384; K = 128; v = bW1[rel]; }
        else                 { int rel = i - 655360; base = 655360 + (rel/32768)*32768;   local = rel%32768; K = 256; v = bWs[rel]; }
        int m = local / K, k = local % K;
        int NKF = K >> 5;
        int mf = m >> 4, r = m & 15;
        int kf = k >> 5, q = (k >> 3) & 3, ii = k & 7;
        int lane = q*16 + r;
        int dst = base + ((mf*NKF + kf)*64 + lane)*8 + ii;
        f16 h, l; split2h(v, h, l);
        f16* W = (f16*)Wswz;
        W[dst] = h; W[WTOT + dst] = l;
        return;
    }

    // ---- KNN ----
    const int b     = blockIdx.x >> 8;
    const int qbase = (blockIdx.x & 255) << 3;
    const int ql    = threadIdx.x >> 5;
    const int sl    = threadIdx.x & 31;
    const float* pb = pts + (size_t)b * N_PTS * 3;
    for (int i = threadIdx.x; i < N_PTS; i += 256) {
        float x = pb[i*3+0], y = pb[i*3+1], z = pb[i*3+2];
        sp[i] = make_float4(x, y, z, x*x + y*y + z*z);
    }
    __syncthreads();

    const int n = qbase + ql;
    const float4 q = sp[n];
    const float4 q2 = make_float4(2.f*q.x, 2.f*q.y, 2.f*q.z, q.w);

    float t[K_D];
#pragma unroll
    for (int s = 0; s < K_D; ++s) t[s] = -INFINITY;

    for (int j = 0; j < N_PTS/32; ++j) {
        float4 c = sp[j*32 + sl];
        float v = neg_dist(q2, c);
#pragma unroll
        for (int s = 0; s < K_D; ++s) {
            float nx = (s < K_D-1) ? t[s+1] : INFINITY;
            t[s] = fminf(fmaxf(t[s], v), nx);
        }
    }

    float head = t[K_D-1];
    float T = -INFINITY;
#pragma unroll 1
    for (int e = 0; e < K_NN; ++e) {
        float v = head; int w = sl;
#pragma unroll
        for (int off = 1; off < 32; off <<= 1) {
            float vo = __shfl_xor(v, off);
            int   wo = __shfl_xor(w, off);
            bool take = (vo > v) || (vo == v && wo < w);
            v = take ? vo : v;
            w = take ? wo : w;
        }
        T = v;
        if (w == sl) {
#pragma unroll
            for (int s = K_D-1; s > 0; --s) t[s] = t[s-1];
            t[0] = -INFINITY;
            head = t[K_D-1];
        }
    }

    float sx = 0.f, sy = 0.f, sz = 0.f;
    for (int j = 0; j < N_PTS/32; ++j) {
        float4 c = sp[j*32 + sl];
        float v = neg_dist(q2, c);
        if (v >= T) { sx += c.x; sy += c.y; sz += c.z; }
    }
#pragma unroll
    for (int off = 1; off < 32; off <<= 1) {
        sx += __shfl_xor(sx, off);
        sy += __shfl_xor(sy, off);
        sz += __shfl_xor(sz, off);
    }
    if (sl == 0) {
        const float inv = 1.0f / (float)K_NN;
        const int pt = b * N_PTS + n;
        m_out[pt*3+0] = sx * inv;
        m_out[pt*3+1] = sy * inv;
        m_out[pt*3+2] = sz * inv;
    }
}

// ---------------------------------------------------------------------------
// MFMA GEMM cores (round-9 measured-good form): runtime NK, compact
// `#pragma unroll 1` kf-loop, Aa/Ab ping-pong. A from L2 (swizzled), B in LDS.
// ---------------------------------------------------------------------------
template<int MF, int JF>
__device__ __forceinline__ void run_gemm_hi(
    const f16* __restrict__ Whi, size_t aoff,
    int NK, const f16* Blds, int bstride, int lane,
    floatx4 (&acc)[MF][JF])
{
    const int l15 = lane & 15;
    const int lq8 = (lane >> 4) * 8;
    half8 Aa[MF], Ab[MF];

    auto loada = [&](half8 (&dst)[MF], int kf) {
#pragma unroll
        for (int fm = 0; fm < MF; ++fm)
            dst[fm] = *(const half8*)(Whi + aoff + (size_t)(fm*NK + kf)*512 + (size_t)lane*8);
    };
    auto step = [&](half8 (&af)[MF], int kf) {
        half8 bq[JF];
#pragma unroll
        for (int fj = 0; fj < JF; ++fj)
            bq[fj] = *(const half8*)&Blds[(fj*16 + l15)*bstride + kf*32 + lq8];
#pragma unroll
        for (int fm = 0; fm < MF; ++fm)
#pragma unroll
            for (int fj = 0; fj < JF; ++fj)
                acc[fm][fj] = __builtin_amdgcn_mfma_f32_16x16x32_f16(af[fm], bq[fj], acc[fm][fj], 0, 0, 0);
    };

    loada(Aa, 0);
#pragma unroll 1
    for (int kf = 0; kf < NK; kf += 2) {
        loada(Ab, kf + 1);
        step(Aa, kf);
        if (kf + 2 < NK) loada(Aa, kf + 2);
        step(Ab, kf + 1);
    }
}

template<int MF, int JF>
__device__ __forceinline__ void run_gemm_split(
    const f16* __restrict__ Whi, const f16* __restrict__ Wlo, size_t aoff,
    int NK, const f16* Blds, int bstride, int lane,
    floatx4 (&acc)[MF][JF], floatx4 (&accL)[MF][JF])
{
    const int l15 = lane & 15;
    const int lq8 = (lane >> 4) * 8;
    half8 Aa[2*MF], Ab[2*MF];

    auto loada = [&](half8 (&dst)[2*MF], int kf) {
#pragma unroll
        for (int fm = 0; fm < MF; ++fm) {
            size_t fo = aoff + (size_t)(fm*NK + kf)*512 + (size_t)lane*8;
            dst[fm*2+0] = *(const half8*)(Whi + fo);
            dst[fm*2+1] = *(const half8*)(Wlo + fo);
        }
    };
    auto step = [&](half8 (&af)[2*MF], int kf) {
        half8 bq[JF];
#pragma unroll
        for (int fj = 0; fj < JF; ++fj)
            bq[fj] = *(const half8*)&Blds[(fj*16 + l15)*bstride + kf*32 + lq8];
#pragma unroll
        for (int fm = 0; fm < MF; ++fm)
#pragma unroll
            for (int fj = 0; fj < JF; ++fj) {
                acc[fm][fj]  = __builtin_amdgcn_mfma_f32_16x16x32_f16(af[fm*2+0], bq[fj], acc[fm][fj], 0, 0, 0);
                accL[fm][fj] = __builtin_amdgcn_mfma_f32_16x16x32_f16(af[fm*2+1], bq[fj], accL[fm][fj], 0, 0, 0);
            }
    };

    loada(Aa, 0);
#pragma unroll 1
    for (int kf = 0; kf < NK; kf += 2) {
        loada(Ab, kf + 1);
        step(Aa, kf);
        if (kf + 2 < NK) loada(Aa, kf + 2);
        step(Ab, kf + 1);
    }
}

__device__ __forceinline__ uint2 pack_res(floatx4 a, floatx4 aL) {
    u16 hh[4];
#pragma unroll
    for (int r = 0; r < 4; ++r) {
        f16 hv = (f16)(a[r] + aL[r] * (1.0f/1024.0f));
        hh[r] = *(u16*)&hv;
    }
    uint2 pv;
    pv.x = (u32)hh[0] | ((u32)hh[1] << 16);
    pv.y = (u32)hh[2] | ((u32)hh[3] << 16);
    return pv;
}

__device__ __forceinline__ uint2 pack_hi(floatx4 a) {
    u16 hh[4];
#pragma unroll
    for (int r = 0; r < 4; ++r) {
        f16 hv = (f16)a[r];
        hh[r] = *(u16*)&hv;
    }
    uint2 pv;
    pv.x = (u32)hh[0] | ((u32)hh[1] << 16);
    pv.y = (u32)hh[2] | ((u32)hh[3] << 16);
    return pv;
}

// ---------------------------------------------------------------------------
// Fused resnet block, 49.5 KB LDS -> 3 blocks/CU (12 waves/CU).
// Trick: gemm4a (Ws@x, split) runs right after gemm1 while x is live in X;
// its accumulators are carried in registers; the X region is then reused for
// h/y2 (stride 136). gemm4b (W1@y2) continues the same accumulators.
// ---------------------------------------------------------------------------
__global__ __launch_bounds__(256, 3) void resblk_kernel(
    const u16* __restrict__ Wswz,
    int offD0, int offW0, int offD1, int offW1, int offWs,
    const f16* __restrict__ netIn, const float* __restrict__ nm_prev,
    const float* __restrict__ pts, const float* __restrict__ m_buf,
    const float* __restrict__ fcW,
    f16* __restrict__ netOut, float* __restrict__ nm_out, int blk0,
    int skip_store)
{
    __shared__ struct {
        f16 X[48*264];                              // x (w256); later h/y2 @136
        union { f16 d[48*264]; float C[48*132]; } Y;// d/y (w256) | d1 @136 | C
    } s;                                            // 50688 B -> 3 blocks/CU

    const int tid  = threadIdx.x;
    const int jb   = blockIdx.x * 48;
    const int bB   = blockIdx.x >> 7;               // batch (128 blocks/batch)
    const int lane = tid & 63;
    const int wv   = tid >> 6;                      // 0..3
    const f16* Whi = (const f16*)Wswz;
    const f16* Wlo = Whi + WTOT;

    // ---- stage x into LDS X (temps in Y region) --------------------------
    if (blk0) {
        float* Hf = (float*)s.Y.C;                  // W(768) p(48)@768 m(48)@816
        const int ptbase = blockIdx.x * 16;
        for (int i = tid; i < 768; i += 256) Hf[i] = fcW[i];
        if (tid < 96) Hf[768 + tid] = (tid < 48) ? pts[ptbase*3 + tid]
                                                 : m_buf[ptbase*3 + tid - 48];
        __syncthreads();
#pragma unroll 1
        for (int it = 0; it < 6; ++it) {
            int idx = tid + 256*it;                 // 0..1535
            int r = idx >> 5;                       // j-row 0..47
            int cg = idx & 31;
            int l = r / 3, v = r - l*3;
            float pv0[3] = {Hf[768+l*3], Hf[768+l*3+1], Hf[768+l*3+2]};
            float mv0[3] = {Hf[816+l*3], Hf[816+l*3+1], Hf[816+l*3+2]};
            int v1 = (v==2) ? 0 : v+1;
            int v2 = (v==0) ? 2 : v-1;
            float av = mv0[v] - pv0[v];
            float bv = pv0[v];
            float cv = mv0[v1]*pv0[v2] - mv0[v2]*pv0[v1];
            half8 o;
#pragma unroll
            for (int k = 0; k < 8; ++k) {
                int ch = cg*8 + k;
                o[k] = (f16)(Hf[ch*3+0]*av + Hf[ch*3+1]*bv + Hf[ch*3+2]*cv);
            }
            *(half8*)&s.X[r*264 + cg*8] = o;
        }
    } else {
#pragma unroll 1
        for (int it = 0; it < 6; ++it) {
            int idx = tid + 256*it;
            int r = idx >> 5;
            int cg = idx & 31;
            if (cg < 16) {
                uint4 vv = *(const uint4*)(netIn + (size_t)(jb + r)*128 + cg*8);
                *(uint4*)&s.X[r*264 + cg*8] = vv;
            } else {
                int v = r % 3;                      // jb % 3 == 0
                const float* np = nm_prev + (bB*3+v)*128 + (cg-16)*8;
                half8 o;
#pragma unroll
                for (int k = 0; k < 8; ++k) o[k] = (f16)(np[k] * (1.0f/2048.0f));
                *(half8*)&s.X[r*264 + cg*8] = o;
            }
        }
    }
    __syncthreads();

    // carried accumulators for net = Ws@x + W1@y2
    floatx4 acc4[2][3], accL4[2][3];
#pragma unroll
    for (int a = 0; a < 2; ++a)
#pragma unroll
        for (int b = 0; b < 3; ++b) { acc4[a][b] = (floatx4){0,0,0,0}; accL4[a][b] = (floatx4){0,0,0,0}; }

    // ---- gemm1: d = D0 @ x (M=256, K=256), hi-only, store d -> Y @264 ----
    {
        floatx4 acc[4][3];
#pragma unroll
        for (int a = 0; a < 4; ++a)
#pragma unroll
            for (int b = 0; b < 3; ++b) acc[a][b] = (floatx4){0,0,0,0};
        run_gemm_hi<4,3>(Whi, (size_t)offD0 + (size_t)wv*16384, 8, s.X, 264, lane, acc);
#pragma unroll
        for (int fm = 0; fm < 4; ++fm)
#pragma unroll
            for (int fj = 0; fj < 3; ++fj) {
                int mloc = wv*64 + fm*16 + (lane>>4)*4;
                int jl   = fj*16 + (lane & 15);
                *(uint2*)&s.Y.d[jl*264 + mloc] = pack_hi(acc[fm][fj]);
            }
    }
    __syncthreads();

    // ---- gemm4a: acc4 = Ws @ x (split), x still live in X ----------------
    run_gemm_split<2,3>(Whi, Wlo, (size_t)offWs + (size_t)wv*8192, 8, s.X, 264, lane, acc4, accL4);

    // ---- relu1: y = vnrelu(x, d), in place in Y (per-thread rows) --------
#pragma unroll 1
    for (int it = 0; it < 2; ++it) {
        int idx = tid + 256*it;
        int l = idx >> 5, cg = idx & 31;
        half8 xa = *(const half8*)&s.X[(l*3+0)*264 + cg*8];
        half8 xb = *(const half8*)&s.X[(l*3+1)*264 + cg*8];
        half8 xc = *(const half8*)&s.X[(l*3+2)*264 + cg*8];
        half8 da = *(const half8*)&s.Y.d[(l*3+0)*264 + cg*8];
        half8 db = *(const half8*)&s.Y.d[(l*3+1)*264 + cg*8];
        half8 dc = *(const half8*)&s.Y.d[(l*3+2)*264 + cg*8];
        half8 ya, yb, yc;
#pragma unroll
        for (int k = 0; k < 8; ++k) {
            float x0 = (float)xa[k], x1 = (float)xb[k], x2 = (float)xc[k];
            float d0 = (float)da[k], d1 = (float)db[k], d2 = (float)dc[k];
            float dot = x0*d0 + x1*d1 + x2*d2;
            float y0, y1, y2;
            if (dot >= 0.f) { y0 = x0; y1 = x1; y2 = x2; }
            else {
                float dsq = d0*d0 + d1*d1 + d2*d2 + 1e-8f;
                float sc = dot / dsq;
                y0 = x0 - sc*d0; y1 = x1 - sc*d1; y2 = x2 - sc*d2;
            }
            ya[k] = (f16)y0; yb[k] = (f16)y1; yc[k] = (f16)y2;
        }
        *(half8*)&s.Y.d[(l*3+0)*264 + cg*8] = ya;
        *(half8*)&s.Y.d[(l*3+1)*264 + cg*8] = yb;
        *(half8*)&s.Y.d[(l*3+2)*264 + cg*8] = yc;
    }
    __syncthreads();          // all waves past gemm4a (X free) and relu1 (y ready)

    // ---- gemm2: h = W0 @ y (split), store h -> X region @136 -------------
    {
        floatx4 acc[2][3], accL[2][3];
#pragma unroll
        for (int a = 0; a < 2; ++a)
#pragma unroll
            for (int b = 0; b < 3; ++b) { acc[a][b] = (floatx4){0,0,0,0}; accL[a][b] = (floatx4){0,0,0,0}; }
        run_gemm_split<2,3>(Whi, Wlo, (size_t)offW0 + (size_t)wv*8192, 8, s.Y.d, 264, lane, acc, accL);
#pragma unroll
        for (int fm = 0; fm < 2; ++fm)
#pragma unroll
            for (int fj = 0; fj < 3; ++fj) {
                int mloc = wv*32 + fm*16 + (lane>>4)*4;
                int jl   = fj*16 + (lane & 15);
                *(uint2*)&s.X[jl*136 + mloc] = pack_res(acc[fm][fj], accL[fm][fj]);
            }
    }
    __syncthreads();

    // ---- gemm3: d1 = D1 @ h (hi-only), store d1 -> Y @136 ----------------
    {
        floatx4 acc[2][3];
#pragma unroll
        for (int a = 0; a < 2; ++a)
#pragma unroll
            for (int b = 0; b < 3; ++b) acc[a][b] = (floatx4){0,0,0,0};
        run_gemm_hi<2,3>(Whi, (size_t)offD1 + (size_t)wv*4096, 4, s.X, 136, lane, acc);
#pragma unroll
        for (int fm = 0; fm < 2; ++fm)
#pragma unroll
            for (int fj = 0; fj < 3; ++fj) {
                int mloc = wv*32 + fm*16 + (lane>>4)*4;
                int jl   = fj*16 + (lane & 15);
                *(uint2*)&s.Y.d[jl*136 + mloc] = pack_hi(acc[fm][fj]);
            }
    }
    __syncthreads();

    // ---- relu2: y2 = vnrelu(h, d1), write over h in X @136 ---------------
    {
        int l = tid >> 4, cg = tid & 15;
        half8 xa = *(const half8*)&s.X[(l*3+0)*136 + cg*8];
        half8 xb = *(const half8*)&s.X[(l*3+1)*136 + cg*8];
        half8 xc = *(const half8*)&s.X[(l*3+2)*136 + cg*8];
        half8 da = *(const half8*)&s.Y.d[(l*3+0)*136 + cg*8];
        half8 db = *(const half8*)&s.Y.d[(l*3+1)*136 + cg*8];
        half8 dc = *(const half8*)&s.Y.d[(l*3+2)*136 + cg*8];
        half8 ya, yb, yc;
#pragma unroll
        for (int k = 0; k < 8; ++k) {
            float x0 = (float)xa[k], x1 = (float)xb[k], x2 = (float)xc[k];
            float d0 = (float)da[k], d1 = (float)db[k], d2 = (float)dc[k];
            float dot = x0*d0 + x1*d1 + x2*d2;
            float y0, y1, y2;
            if (dot >= 0.f) { y0 = x0; y1 = x1; y2 = x2; }
            else {
                float dsq = d0*d0 + d1*d1 + d2*d2 + 1e-8f;
                float sc = dot / dsq;
                y0 = x0 - sc*d0; y1 = x1 - sc*d1; y2 = x2 - sc*d2;
            }
            ya[k] = (f16)y0; yb[k] = (f16)y1; yc[k] = (f16)y2;
        }
        __syncthreads();
        *(half8*)&s.X[(l*3+0)*136 + cg*8] = ya;
        *(half8*)&s.X[(l*3+1)*136 + cg*8] = yb;
        *(half8*)&s.X[(l*3+2)*136 + cg*8] = yc;
    }
    __syncthreads();

    // ---- gemm4b: acc4 += W1 @ y2 (split), B = X @136 ---------------------
    run_gemm_split<2,3>(Whi, Wlo, (size_t)offW1 + (size_t)wv*4096, 4, s.X, 136, lane, acc4, accL4);

    // ---- epilogue: store net + stage C floats into Y region --------------
#pragma unroll
    for (int fm = 0; fm < 2; ++fm)
#pragma unroll
        for (int fj = 0; fj < 3; ++fj) {
            int mloc = wv*32 + fm*16 + (lane>>4)*4;
            int jl   = fj*16 + (lane & 15);
            floatx4 res;
#pragma unroll
            for (int r = 0; r < 4; ++r) res[r] = acc4[fm][fj][r] + accL4[fm][fj][r] * (1.0f/1024.0f);
            if (!skip_store) {
                u16 hh[4];
#pragma unroll
                for (int r = 0; r < 4; ++r) { f16 hv = (f16)res[r]; hh[r] = *(u16*)&hv; }
                uint2 pv;
                pv.x = (u32)hh[0] | ((u32)hh[1] << 16);
                pv.y = (u32)hh[2] | ((u32)hh[3] << 16);
                *(uint2*)(netOut + (size_t)(jb + jl)*128 + mloc) = pv;
            }
            *(floatx4*)&s.Y.C[jl*132 + mloc] = res;
        }
    __syncthreads();

    // ---- pool: sum over 16 points per (v, ch), atomic into nm_out --------
#pragma unroll 1
    for (int idx = tid; idx < 384; idx += 256) {
        int v = idx >> 7, ch = idx & 127;
        float sum = 0.f;
#pragma unroll 1
        for (int pt = 0; pt < 16; ++pt) sum += s.Y.C[(pt*3+v)*132 + ch];
        atomicAdd(nm_out + (bB*3+v)*128 + ch, sum);
    }
}

// ---------------------------------------------------------------------------
// Final head (separate dispatch, R9-verified): reads raw pool sums (/2048).
// ---------------------------------------------------------------------------
__global__ __launch_bounds__(128) void final_kernel(const float* __restrict__ nm_sum,
                                                    const float* __restrict__ act_d,
                                                    const float* __restrict__ fc_c,
                                                    float* __restrict__ out)
{
    const int b = blockIdx.x;
    const int c = threadIdx.x;
    __shared__ float xs[128][3];
    __shared__ float ys[128][3];
    xs[c][0] = nm_sum[(b*3+0)*128 + c] * (1.0f/2048.0f);
    xs[c][1] = nm_sum[(b*3+1)*128 + c] * (1.0f/2048.0f);
    xs[c][2] = nm_sum[(b*3+2)*128 + c] * (1.0f/2048.0f);
    __syncthreads();
    float d0 = 0.f, d1 = 0.f, d2 = 0.f;
    for (int i = 0; i < 128; ++i) {
        float w = act_d[c*128 + i];
        d0 = fmaf(w, xs[i][0], d0);
        d1 = fmaf(w, xs[i][1], d1);
        d2 = fmaf(w, xs[i][2], d2);
    }
    float x0 = xs[c][0], x1 = xs[c][1], x2 = xs[c][2];
    float dot = x0*d0 + x1*d1 + x2*d2;
    float y0, y1, y2;
    if (dot >= 0.f) { y0 = x0; y1 = x1; y2 = x2; }
    else {
        float dsq = d0*d0 + d1*d1 + d2*d2 + 1e-8f;
        float sc = dot / dsq;
        y0 = x0 - sc*d0; y1 = x1 - sc*d1; y2 = x2 - sc*d2;
    }
    ys[c][0] = y0; ys[c][1] = y1; ys[c][2] = y2;
    __syncthreads();
    float o0 = 0.f, o1 = 0.f, o2 = 0.f;
    for (int i = 0; i < 128; ++i) {
        float w = fc_c[c*128 + i];
        o0 = fmaf(w, ys[i][0], o0);
        o1 = fmaf(w, ys[i][1], o1);
        o2 = fmaf(w, ys[i][2], o2);
    }
    out[b*384 + c*3 + 0] = o0;
    out[b*384 + c*3 + 1] = o1;
    out[b*384 + c*3 + 2] = o2;
}

// ---------------------------------------------------------------------------
extern "C" void kernel_launch(void* const* d_in, const int* in_sizes, int n_in,
                              void* d_out, int out_size, void* d_ws, size_t ws_size,
                              hipStream_t stream)
{
    const float* p      = (const float*)d_in[0];
    const float* fc_pos = (const float*)d_in[1];
    const float* bd0    = (const float*)d_in[2];
    const float* bW0    = (const float*)d_in[3];
    const float* bd1    = (const float*)d_in[4];
    const float* bW1    = (const float*)d_in[5];
    const float* bWs    = (const float*)d_in[6];
    const float* fc_c   = (const float*)d_in[7];
    const float* act_d  = (const float*)d_in[8];
    float* out = (float*)d_out;

    // Workspace layout (16B-aligned)
    char* w = (char*)d_ws;
    float* m_buf  = (float*)w;  w += 98304;                  // knn means
    float* nm_acc = (float*)w;  w += 5*1536*4;               // pool sums
    u16*   Wswz   = (u16*)w;    w += (size_t)2*WTOT*2;       // swizzled split weights
    f16*   netA   = (f16*)w;    w += (size_t)24576*128*2;
    f16*   netB   = (f16*)w;    w += (size_t)24576*128*2;

    prep_kernel<<<dim3(1024 + 3200), dim3(256), 0, stream>>>(
        p, m_buf, bd0, bW0, bd1, bW1, bWs, Wswz, nm_acc);

    f16* nIn = netA;
    f16* nOut = netB;
    for (int blk = 0; blk < 5; ++blk) {
        const int offD0 = blk*65536;
        const int offW0 = 327680 + blk*32768;
        const int offD1 = 491520 + blk*16384;
        const int offW1 = 573440 + blk*16384;
        const int offWs = 655360 + blk*32768;
        const float* nmp = (blk == 0) ? nullptr : (nm_acc + (blk-1)*1536);
        resblk_kernel<<<dim3(512), dim3(256), 0, stream>>>(
            Wswz, offD0, offW0, offD1, offW1, offWs,
            (blk == 0) ? netA : nIn, nmp, p, m_buf, fc_pos,
            nOut, nm_acc + blk*1536, (blk == 0) ? 1 : 0,
            (blk == 4) ? 1 : 0);
        f16* tmp = nIn; nIn = nOut; nOut = tmp;
    }

    final_kernel<<<dim3(4), dim3(128), 0, stream>>>(nm_acc + 4*1536, act_d, fc_c, out);

    (void)in_sizes; (void)n_in; (void)out_size; (void)ws_size;
}